// Round 2
// baseline (437.974 us; speedup 1.0000x reference)
//
#include <hip/hip_runtime.h>

// Problem constants (from reference): N=262144 rows, NX=NQ=64, NU=16, fp32.
#define NROWS 262144

// d_ws layout (floats):
//   AT   [4096]  @ 0      : AT[j*64+k]  = A[k][j]
//   C1T  [4096]  @ 4096   : C1T[j*64+i] = C1[i][j]
//   D11T [4096]  @ 8192   : D11T[i*64+k]= D11[k][i]
//   B1T  [4096]  @ 12288  : B1T[i*64+k] = B1[k][i]
//   B2T  [1024]  @ 16384  : B2T[j*64+k] = B2[k][j]
//   D12T [1024]  @ 17408  : D12T[j*64+i]= D12[i][j]
//   bv   [64]    @ 18432
//   bx   [64]    @ 18496

__global__ void prep_kernel(const float* __restrict__ A, const float* __restrict__ B1,
                            const float* __restrict__ B2, const float* __restrict__ C1,
                            const float* __restrict__ D11, const float* __restrict__ D12,
                            const float* __restrict__ bv, const float* __restrict__ bx,
                            float* __restrict__ ws) {
    int g = blockIdx.x * 256 + threadIdx.x;
    // 16 blocks x 256 threads = 4096 threads; one element of each big matrix.
    if (g < 4096) {
        int r = g >> 6, c = g & 63;
        int to = c * 64 + r;
        ws[0 * 4096 + to] = A[g];
        ws[1 * 4096 + to] = C1[g];
        ws[2 * 4096 + to] = D11[g];
        ws[3 * 4096 + to] = B1[g];
    }
    if (g < 1024) {
        int r = g >> 4, c = g & 15;   // 64x16 row-major in
        int to = c * 64 + r;
        ws[16384 + to] = B2[g];
        ws[17408 + to] = D12[g];
    }
    if (g < 64) {
        ws[18432 + g] = bv[g];
        ws[18496 + g] = bx[g];
    }
}

// One thread per row, three phases, peak live state ~90 VGPRs, no LDS.
__global__ __launch_bounds__(256, 4) void renl2_kernel(const float* __restrict__ x,
                                                       const float* __restrict__ u,
                                                       const float* __restrict__ ws,
                                                       float* __restrict__ out) {
    const float* __restrict__ AT   = ws;
    const float* __restrict__ C1T  = ws + 4096;
    const float* __restrict__ D11T = ws + 8192;
    const float* __restrict__ B1T  = ws + 12288;
    const float* __restrict__ B2T  = ws + 16384;
    const float* __restrict__ D12T = ws + 17408;
    const float* __restrict__ bv   = ws + 18432;
    const float* __restrict__ bx   = ws + 18496;

    const long n = (long)blockIdx.x * 256 + threadIdx.x;
    const float* __restrict__ xr = x + n * 64;
    const float* __restrict__ ur = u + n * 16;

    // Phase 1: s = bv + C1 x + D12 u   (64 live floats; matrices via uniform s_load)
    float s[64];
#pragma unroll
    for (int i = 0; i < 64; i++) s[i] = bv[i];

#pragma unroll 1
    for (int j = 0; j < 64; j += 4) {
        float4 xv = *(const float4*)(xr + j);
#pragma unroll
        for (int jj = 0; jj < 4; jj++) {
            const float xs = ((const float*)&xv)[jj];
            const float* __restrict__ cc = C1T + (j + jj) * 64;
#pragma unroll
            for (int i = 0; i < 64; i++) s[i] += cc[i] * xs;
        }
    }
#pragma unroll 1
    for (int j = 0; j < 16; j += 4) {
        float4 uv = *(const float4*)(ur + j);
#pragma unroll
        for (int jj = 0; jj < 4; jj++) {
            const float us = ((const float*)&uv)[jj];
            const float* __restrict__ dc = D12T + (j + jj) * 64;
#pragma unroll
            for (int i = 0; i < 64; i++) s[i] += dc[i] * us;
        }
    }

    // Phase 2: forward substitution in place; s becomes w = relu(...).
#pragma unroll
    for (int i = 0; i < 64; i++) {
        s[i] = fmaxf(s[i], 0.0f);
        const float wv = s[i];
        const float* __restrict__ dcol = D11T + i * 64;
#pragma unroll
        for (int k = i + 1; k < 64; k++) s[k] += dcol[k] * wv;
    }

    // Phase 3: x_dot in 4 chunks of 16; x,u re-streamed (L1/L2 hot), w in regs.
#pragma unroll 1
    for (int c = 0; c < 4; c++) {
        const int c16 = c * 16;
        float acc[16];
#pragma unroll
        for (int k = 0; k < 16; k++) acc[k] = bx[c16 + k];

        // acc += A_c x
#pragma unroll 1
        for (int j = 0; j < 64; j += 4) {
            float4 xv = *(const float4*)(xr + j);
#pragma unroll
            for (int jj = 0; jj < 4; jj++) {
                const float xs = ((const float*)&xv)[jj];
                const float* __restrict__ ac = AT + (j + jj) * 64 + c16;
#pragma unroll
                for (int k = 0; k < 16; k++) acc[k] += ac[k] * xs;
            }
        }
        // acc += B2_c u
#pragma unroll 1
        for (int j = 0; j < 16; j += 4) {
            float4 uv = *(const float4*)(ur + j);
#pragma unroll
            for (int jj = 0; jj < 4; jj++) {
                const float us = ((const float*)&uv)[jj];
                const float* __restrict__ bc = B2T + (j + jj) * 64 + c16;
#pragma unroll
                for (int k = 0; k < 16; k++) acc[k] += bc[k] * us;
            }
        }
        // acc += B1_c w  (i fully unrolled so s[i] stays const-indexed in regs)
#pragma unroll
        for (int i = 0; i < 64; i++) {
            const float* __restrict__ b1c = B1T + i * 64 + c16;
            const float wv = s[i];
#pragma unroll
            for (int k = 0; k < 16; k++) acc[k] += b1c[k] * wv;
        }

        // Store chunk.
        float4* __restrict__ op = (float4*)(out + n * 64 + c16);
#pragma unroll
        for (int k = 0; k < 16; k += 4) {
            float4 v;
            v.x = acc[k]; v.y = acc[k + 1]; v.z = acc[k + 2]; v.w = acc[k + 3];
            op[k >> 2] = v;
        }
    }
}

extern "C" void kernel_launch(void* const* d_in, const int* in_sizes, int n_in,
                              void* d_out, int out_size, void* d_ws, size_t ws_size,
                              hipStream_t stream) {
    const float* x   = (const float*)d_in[0];
    const float* u   = (const float*)d_in[1];
    const float* A   = (const float*)d_in[2];
    const float* B1  = (const float*)d_in[3];
    const float* B2  = (const float*)d_in[4];
    const float* C1  = (const float*)d_in[5];
    const float* D11 = (const float*)d_in[6];
    const float* D12 = (const float*)d_in[7];
    const float* bv  = (const float*)d_in[8];
    const float* bx  = (const float*)d_in[9];
    float* out = (float*)d_out;
    float* ws  = (float*)d_ws;

    prep_kernel<<<16, 256, 0, stream>>>(A, B1, B2, C1, D11, D12, bv, bx, ws);
    renl2_kernel<<<NROWS / 256, 256, 0, stream>>>(x, u, ws, out);
}

// Round 3
// 412.230 us; speedup vs baseline: 1.0624x; 1.0624x over previous
//
#include <hip/hip_runtime.h>

// Problem constants: N=262144 rows, NX=NQ=64, NU=16, fp32.
#define NROWS 262144
#define T 128  // threads per block

typedef float f16v __attribute__((ext_vector_type(16)));
#define LD16(p) (*(const f16v*)(p))

// d_ws layout (floats):
//   AT   [4096]  @ 0      : AT[j*64+k]  = A[k][j]
//   C1T  [4096]  @ 4096   : C1T[j*64+i] = C1[i][j]
//   D11T [4096]  @ 8192   : D11T[i*64+k]= D11[k][i]   (col i of D11; 0 for k<=i)
//   B1T  [4096]  @ 12288  : B1T[i*64+k] = B1[k][i]
//   B2T  [1024]  @ 16384  : B2T[j*64+k] = B2[k][j]
//   D12T [1024]  @ 17408  : D12T[j*64+i]= D12[i][j]
//   bv   [64]    @ 18432
//   bx   [64]    @ 18496

__global__ void prep_kernel(const float* __restrict__ A, const float* __restrict__ B1,
                            const float* __restrict__ B2, const float* __restrict__ C1,
                            const float* __restrict__ D11, const float* __restrict__ D12,
                            const float* __restrict__ bv, const float* __restrict__ bx,
                            float* __restrict__ ws) {
    int g = blockIdx.x * 256 + threadIdx.x;
    if (g < 4096) {
        int r = g >> 6, c = g & 63;
        int to = c * 64 + r;
        ws[0 * 4096 + to] = A[g];
        ws[1 * 4096 + to] = C1[g];
        ws[2 * 4096 + to] = D11[g];
        ws[3 * 4096 + to] = B1[g];
    }
    if (g < 1024) {
        int r = g >> 4, c = g & 15;   // 64x16 row-major in
        int to = c * 64 + r;
        ws[16384 + to] = B2[g];
        ws[17408 + to] = D12[g];
    }
    if (g < 64) {
        ws[18432 + g] = bv[g];
        ws[18496 + g] = bx[g];
    }
}

// One thread per row. State held in NAMED ext-vector values (SSA, no SROA
// failure possible): s0..s3 = w precursor, a0..a3 = x_dot accumulator.
__global__ __launch_bounds__(T, 2) void renl2_kernel(const float* __restrict__ x,
                                                     const float* __restrict__ u,
                                                     const float* __restrict__ ws,
                                                     float* __restrict__ out) {
    const float* __restrict__ AT   = ws;
    const float* __restrict__ C1T  = ws + 4096;
    const float* __restrict__ D11T = ws + 8192;
    const float* __restrict__ B1T  = ws + 12288;
    const float* __restrict__ B2T  = ws + 16384;
    const float* __restrict__ D12T = ws + 17408;
    const float* __restrict__ bv   = ws + 18432;
    const float* __restrict__ bx   = ws + 18496;

    // w_lds[i*T + tid]: lanes consecutive -> conflict-free; same-thread RAW only.
    __shared__ float w_lds[64 * T];

    const int tid = threadIdx.x;
    const int n = blockIdx.x * T + tid;
    const float* __restrict__ xr = x + (size_t)n * 64;
    const float* __restrict__ ur = u + (size_t)n * 16;

    f16v s0 = LD16(bv), s1 = LD16(bv + 16), s2 = LD16(bv + 32), s3 = LD16(bv + 48);
    f16v a0 = LD16(bx), a1 = LD16(bx + 16), a2 = LD16(bx + 32), a3 = LD16(bx + 48);

    // ---- x pass: s += C1 x ; a += A x  (x streamed once, manual prefetch) ----
    float4 xv = *(const float4*)(xr);
#pragma unroll 1
    for (int j = 0; j < 64; j += 4) {
        const float4 xn = *(const float4*)(xr + ((j + 4) & 63));
        const float* __restrict__ cb = C1T + j * 64;
        const float* __restrict__ ab = AT + j * 64;
#pragma unroll
        for (int jj = 0; jj < 4; jj++) {
            const float xs = (jj == 0) ? xv.x : (jj == 1) ? xv.y : (jj == 2) ? xv.z : xv.w;
            const float* cc = cb + jj * 64;
            const float* ac = ab + jj * 64;
            s0 += LD16(cc) * xs; s1 += LD16(cc + 16) * xs; s2 += LD16(cc + 32) * xs; s3 += LD16(cc + 48) * xs;
            a0 += LD16(ac) * xs; a1 += LD16(ac + 16) * xs; a2 += LD16(ac + 32) * xs; a3 += LD16(ac + 48) * xs;
        }
        xv = xn;
    }

    // ---- u pass: s += D12 u ; a += B2 u ----
    float4 uv = *(const float4*)(ur);
#pragma unroll 1
    for (int j = 0; j < 16; j += 4) {
        const float4 un = *(const float4*)(ur + ((j + 4) & 15));
        const float* __restrict__ db = D12T + j * 64;
        const float* __restrict__ bb = B2T + j * 64;
#pragma unroll
        for (int jj = 0; jj < 4; jj++) {
            const float us = (jj == 0) ? uv.x : (jj == 1) ? uv.y : (jj == 2) ? uv.z : uv.w;
            const float* dc = db + jj * 64;
            const float* bc = bb + jj * 64;
            s0 += LD16(dc) * us; s1 += LD16(dc + 16) * us; s2 += LD16(dc + 32) * us; s3 += LD16(dc + 48) * us;
            a0 += LD16(bc) * us; a1 += LD16(bc + 16) * us; a2 += LD16(bc + 32) * us; a3 += LD16(bc + 48) * us;
        }
        uv = un;
    }

    // ---- forward substitution; s becomes w = relu(...). ----
    // In-chunk step: finalize w_i, store to LDS, apply column i to the rest of
    // this chunk as a 16-wide FMA (entries at rows <= i are exact zeros).
#define SUBSTEP(sc, c, ii) { \
        const float wv = fmaxf(sc[ii], 0.0f); sc[ii] = wv; \
        w_lds[((c) * 16 + (ii)) * T + tid] = wv; \
        sc += LD16(D11T + ((c) * 16 + (ii)) * 64 + (c) * 16) * wv; }
#define R16(M, sc, c) M(sc,c,0) M(sc,c,1) M(sc,c,2) M(sc,c,3) M(sc,c,4) M(sc,c,5) M(sc,c,6) M(sc,c,7) \
                      M(sc,c,8) M(sc,c,9) M(sc,c,10) M(sc,c,11) M(sc,c,12) M(sc,c,13) M(sc,c,14) M(sc,c,15)

    R16(SUBSTEP, s0, 0)
#pragma unroll 1
    for (int i = 0; i < 16; i++) {   // cross: chunk0 -> chunks 1..3
        const float wv = w_lds[i * T + tid];
        const float* db = D11T + i * 64;
        s1 += LD16(db + 16) * wv; s2 += LD16(db + 32) * wv; s3 += LD16(db + 48) * wv;
    }
    R16(SUBSTEP, s1, 1)
#pragma unroll 1
    for (int i = 16; i < 32; i++) {  // cross: chunk1 -> chunks 2..3
        const float wv = w_lds[i * T + tid];
        const float* db = D11T + i * 64;
        s2 += LD16(db + 32) * wv; s3 += LD16(db + 48) * wv;
    }
    R16(SUBSTEP, s2, 2)
#pragma unroll 1
    for (int i = 32; i < 48; i++) {  // cross: chunk2 -> chunk 3
        const float wv = w_lds[i * T + tid];
        const float* db = D11T + i * 64;
        s3 += LD16(db + 48) * wv;
    }
    R16(SUBSTEP, s3, 3)

    // ---- a += B1 w  (w re-read from LDS; s chunks dead here) ----
#pragma unroll 2
    for (int i = 0; i < 64; i++) {
        const float wv = w_lds[i * T + tid];
        const float* bb = B1T + i * 64;
        a0 += LD16(bb) * wv; a1 += LD16(bb + 16) * wv; a2 += LD16(bb + 32) * wv; a3 += LD16(bb + 48) * wv;
    }

    // ---- store x_dot row ----
    float* op = out + (size_t)n * 64;
    *(f16v*)(op) = a0; *(f16v*)(op + 16) = a1; *(f16v*)(op + 32) = a2; *(f16v*)(op + 48) = a3;
}

extern "C" void kernel_launch(void* const* d_in, const int* in_sizes, int n_in,
                              void* d_out, int out_size, void* d_ws, size_t ws_size,
                              hipStream_t stream) {
    const float* x   = (const float*)d_in[0];
    const float* u   = (const float*)d_in[1];
    const float* A   = (const float*)d_in[2];
    const float* B1  = (const float*)d_in[3];
    const float* B2  = (const float*)d_in[4];
    const float* C1  = (const float*)d_in[5];
    const float* D11 = (const float*)d_in[6];
    const float* D12 = (const float*)d_in[7];
    const float* bv  = (const float*)d_in[8];
    const float* bx  = (const float*)d_in[9];
    float* out = (float*)d_out;
    float* ws  = (float*)d_ws;

    prep_kernel<<<16, 256, 0, stream>>>(A, B1, B2, C1, D11, D12, bv, bx, ws);
    renl2_kernel<<<NROWS / T, T, 0, stream>>>(x, u, ws, out);
}

// Round 4
// 317.011 us; speedup vs baseline: 1.3816x; 1.3004x over previous
//
#include <hip/hip_runtime.h>
#include <utility>

// Problem constants: N=262144 rows, NX=NQ=64, NU=16, fp32.
#define NROWS 262144
#define T 256

typedef float f16v __attribute__((ext_vector_type(16)));
#define LD16(p) (*(const f16v*)(p))

// d_ws layout (floats):
//   AT   [4096]  @ 0      : AT[j*64+k]  = A[k][j]
//   C1T  [4096]  @ 4096   : C1T[j*64+i] = C1[i][j]
//   D11T [4096]  @ 8192   : D11T[i*64+k]= D11[k][i]   (col i of D11; 0 for k<=i)
//   B1T  [4096]  @ 12288  : B1T[i*64+k] = B1[k][i]
//   B2T  [1024]  @ 16384  : B2T[j*64+k] = B2[k][j]
//   D12T [1024]  @ 17408  : D12T[j*64+i]= D12[i][j]
//   bv   [64]    @ 18432
//   bx   [64]    @ 18496

__global__ void prep_kernel(const float* __restrict__ A, const float* __restrict__ B1,
                            const float* __restrict__ B2, const float* __restrict__ C1,
                            const float* __restrict__ D11, const float* __restrict__ D12,
                            const float* __restrict__ bv, const float* __restrict__ bx,
                            float* __restrict__ ws) {
    int g = blockIdx.x * 256 + threadIdx.x;
    if (g < 4096) {
        int r = g >> 6, c = g & 63;
        int to = c * 64 + r;
        ws[0 * 4096 + to] = A[g];
        ws[1 * 4096 + to] = C1[g];
        ws[2 * 4096 + to] = D11[g];
        ws[3 * 4096 + to] = B1[g];
    }
    if (g < 1024) {
        int r = g >> 4, c = g & 15;   // 64x16 row-major in
        int to = c * 64 + r;
        ws[16384 + to] = B2[g];
        ws[17408 + to] = D12[g];
    }
    if (g < 64) {
        ws[18432 + g] = bv[g];
        ws[18496 + g] = bx[g];
    }
}

// ---- substitution step I: finalize w_I = relu(s_I), scatter D11 column I into
// rows > I. Only the f16v slots that contain rows > I are touched (if constexpr).
template<int I>
__device__ __forceinline__ void substep(f16v& s0, f16v& s1, f16v& s2, f16v& s3,
                                        const float* __restrict__ D11T) {
    constexpr int vi = I >> 4, e = I & 15;
    float v;
    if constexpr (vi == 0) v = s0[e];
    else if constexpr (vi == 1) v = s1[e];
    else if constexpr (vi == 2) v = s2[e];
    else v = s3[e];
    const float wv = fmaxf(v, 0.0f);
    if constexpr (vi == 0) s0[e] = wv;
    else if constexpr (vi == 1) s1[e] = wv;
    else if constexpr (vi == 2) s2[e] = wv;
    else s3[e] = wv;
    const float* col = D11T + I * 64;
    if constexpr (I < 15) s0 += LD16(col) * wv;
    if constexpr (I < 31) s1 += LD16(col + 16) * wv;
    if constexpr (I < 47) s2 += LD16(col + 32) * wv;
    if constexpr (I < 63) s3 += LD16(col + 48) * wv;
}

template<int... Is>
__device__ __forceinline__ void subst_all(f16v& s0, f16v& s1, f16v& s2, f16v& s3,
                                          const float* __restrict__ D11T,
                                          std::integer_sequence<int, Is...>) {
    (substep<Is>(s0, s1, s2, s3, D11T), ...);
}

// ---- Kernel A: w = forward_subst(bv + C1 x + D12 u), written to wout (= d_out).
// State: s only (64 floats) -> ~96 VGPR, no LDS -> high occupancy.
__global__ __launch_bounds__(T, 4) void w_kernel(const float* __restrict__ x,
                                                 const float* __restrict__ u,
                                                 const float* __restrict__ ws,
                                                 float* __restrict__ wout) {
    const float* __restrict__ C1T  = ws + 4096;
    const float* __restrict__ D11T = ws + 8192;
    const float* __restrict__ D12T = ws + 17408;
    const float* __restrict__ bv   = ws + 18432;

    const int n = blockIdx.x * T + threadIdx.x;
    const float* __restrict__ xr = x + (size_t)n * 64;
    const float* __restrict__ ur = u + (size_t)n * 16;

    f16v s0 = LD16(bv), s1 = LD16(bv + 16), s2 = LD16(bv + 32), s3 = LD16(bv + 48);

#pragma unroll 1
    for (int j = 0; j < 64; j += 4) {
        const float4 xv = *(const float4*)(xr + j);
#pragma unroll
        for (int jj = 0; jj < 4; jj++) {
            const float xs = (jj == 0) ? xv.x : (jj == 1) ? xv.y : (jj == 2) ? xv.z : xv.w;
            const float* cc = C1T + (j + jj) * 64;
            s0 += LD16(cc) * xs; s1 += LD16(cc + 16) * xs;
            s2 += LD16(cc + 32) * xs; s3 += LD16(cc + 48) * xs;
        }
    }
#pragma unroll 1
    for (int j = 0; j < 16; j += 4) {
        const float4 uv = *(const float4*)(ur + j);
#pragma unroll
        for (int jj = 0; jj < 4; jj++) {
            const float us = (jj == 0) ? uv.x : (jj == 1) ? uv.y : (jj == 2) ? uv.z : uv.w;
            const float* dc = D12T + (j + jj) * 64;
            s0 += LD16(dc) * us; s1 += LD16(dc + 16) * us;
            s2 += LD16(dc + 32) * us; s3 += LD16(dc + 48) * us;
        }
    }

    subst_all(s0, s1, s2, s3, D11T, std::make_integer_sequence<int, 64>{});

    float* op = wout + (size_t)n * 64;
    *(f16v*)(op) = s0; *(f16v*)(op + 16) = s1;
    *(f16v*)(op + 32) = s2; *(f16v*)(op + 48) = s3;
}

// ---- Kernel B: out = bx + A x + B2 u + B1 w. Reads w from wo (= d_out) and
// overwrites the same row (same thread reads then writes -> safe, no restrict).
__global__ __launch_bounds__(T, 4) void out_kernel(const float* __restrict__ x,
                                                   const float* __restrict__ u,
                                                   const float* __restrict__ ws,
                                                   float* wo) {
    const float* __restrict__ AT  = ws;
    const float* __restrict__ B1T = ws + 12288;
    const float* __restrict__ B2T = ws + 16384;
    const float* __restrict__ bx  = ws + 18496;

    const int n = blockIdx.x * T + threadIdx.x;
    const float* __restrict__ xr = x + (size_t)n * 64;
    const float* __restrict__ ur = u + (size_t)n * 16;
    float* wr = wo + (size_t)n * 64;

    f16v a0 = LD16(bx), a1 = LD16(bx + 16), a2 = LD16(bx + 32), a3 = LD16(bx + 48);

#pragma unroll 1
    for (int j = 0; j < 64; j += 4) {
        const float4 xv = *(const float4*)(xr + j);
#pragma unroll
        for (int jj = 0; jj < 4; jj++) {
            const float xs = (jj == 0) ? xv.x : (jj == 1) ? xv.y : (jj == 2) ? xv.z : xv.w;
            const float* ac = AT + (j + jj) * 64;
            a0 += LD16(ac) * xs; a1 += LD16(ac + 16) * xs;
            a2 += LD16(ac + 32) * xs; a3 += LD16(ac + 48) * xs;
        }
    }
#pragma unroll 1
    for (int j = 0; j < 16; j += 4) {
        const float4 uv = *(const float4*)(ur + j);
#pragma unroll
        for (int jj = 0; jj < 4; jj++) {
            const float us = (jj == 0) ? uv.x : (jj == 1) ? uv.y : (jj == 2) ? uv.z : uv.w;
            const float* bc = B2T + (j + jj) * 64;
            a0 += LD16(bc) * us; a1 += LD16(bc + 16) * us;
            a2 += LD16(bc + 32) * us; a3 += LD16(bc + 48) * us;
        }
    }
#pragma unroll 1
    for (int j = 0; j < 64; j += 4) {
        const float4 wv = *(const float4*)(wr + j);
#pragma unroll
        for (int jj = 0; jj < 4; jj++) {
            const float wsc = (jj == 0) ? wv.x : (jj == 1) ? wv.y : (jj == 2) ? wv.z : wv.w;
            const float* bc = B1T + (j + jj) * 64;
            a0 += LD16(bc) * wsc; a1 += LD16(bc + 16) * wsc;
            a2 += LD16(bc + 32) * wsc; a3 += LD16(bc + 48) * wsc;
        }
    }

    *(f16v*)(wr) = a0; *(f16v*)(wr + 16) = a1;
    *(f16v*)(wr + 32) = a2; *(f16v*)(wr + 48) = a3;
}

extern "C" void kernel_launch(void* const* d_in, const int* in_sizes, int n_in,
                              void* d_out, int out_size, void* d_ws, size_t ws_size,
                              hipStream_t stream) {
    const float* x   = (const float*)d_in[0];
    const float* u   = (const float*)d_in[1];
    const float* A   = (const float*)d_in[2];
    const float* B1  = (const float*)d_in[3];
    const float* B2  = (const float*)d_in[4];
    const float* C1  = (const float*)d_in[5];
    const float* D11 = (const float*)d_in[6];
    const float* D12 = (const float*)d_in[7];
    const float* bv  = (const float*)d_in[8];
    const float* bx  = (const float*)d_in[9];
    float* out = (float*)d_out;
    float* ws  = (float*)d_ws;

    prep_kernel<<<16, 256, 0, stream>>>(A, B1, B2, C1, D11, D12, bv, bx, ws);
    w_kernel<<<NROWS / T, T, 0, stream>>>(x, u, ws, out);     // w -> d_out
    out_kernel<<<NROWS / T, T, 0, stream>>>(x, u, ws, out);   // d_out -> x_dot
}